// Round 1
// baseline (610.758 us; speedup 1.0000x reference)
//
#include <hip/hip_runtime.h>

// Problem constants (match reference)
constexpr int T = 4;
constexpr int E = 250000;
constexpr int D = 128;      // embedding dim
constexpr int B = 4096;     // batch
constexpr int L = 50;       // bag length

// One wave (64 lanes) per (table, sample) bag.
// Lane i accumulates output dims [2i, 2i+1] as float2.
// Gather per row: 64 lanes x float2 = 512B contiguous = the full D=128 row.
__global__ __launch_bounds__(256) void embbag_sum_kernel(
    const float* __restrict__ weights,   // [T, E, D]
    const int*   __restrict__ indices,   // [T, B, L]
    float*       __restrict__ out)       // [B, T*D]
{
    const int wave = threadIdx.x >> 6;          // 0..3
    const int lane = threadIdx.x & 63;
    const int g    = (blockIdx.x << 2) + wave;  // bag id in [0, T*B)
    const int t    = g >> 12;                   // / B (B = 4096)
    const int b    = g & (B - 1);               // % B

    const int*   idx = indices + ((size_t)t * B + b) * L;
    const float* wt  = weights + (size_t)t * E * D;

    float2 acc = make_float2(0.f, 0.f);

    // L = 50 = 5 chunks of 10: 10 independent gathers in flight per wave.
    #pragma unroll 1
    for (int l0 = 0; l0 < L; l0 += 10) {
        int rows[10];
        #pragma unroll
        for (int u = 0; u < 10; ++u) {
            // indices are wave-uniform -> pin to SGPR so the gather becomes
            // global_load_dwordx2 with scalar base + lane voffset.
            rows[u] = __builtin_amdgcn_readfirstlane(idx[l0 + u]);
        }
        #pragma unroll
        for (int u = 0; u < 10; ++u) {
            const float2 v =
                *((const float2*)(wt + (size_t)rows[u] * D) + lane);
            acc.x += v.x;
            acc.y += v.y;
        }
    }

    // out[b][t*D + 2*lane .. +1], 512B contiguous per wave.
    float2* o = (float2*)(out + (size_t)b * (T * D) + t * D) + lane;
    *o = acc;
}

extern "C" void kernel_launch(void* const* d_in, const int* in_sizes, int n_in,
                              void* d_out, int out_size, void* d_ws, size_t ws_size,
                              hipStream_t stream) {
    const float* weights = (const float*)d_in[0];
    const int*   indices = (const int*)d_in[1];
    float*       out     = (float*)d_out;

    const int bags   = T * B;            // 16384
    const int blocks = bags / 4;         // 4 waves (bags) per 256-thread block
    embbag_sum_kernel<<<blocks, 256, 0, stream>>>(weights, indices, out);
}